// Round 8
// baseline (1338.762 us; speedup 1.0000x reference)
//
#include <hip/hip_runtime.h>

#define M_ROWS 200000
#define NROWS  64            // rows per block
#define NBLK   3125          // 200000 / 64, exact
#define DIM1   320
#define OUTD   416
#define FSTR   196           // feat row stride (floats)

#define SCAL_STR 9
#define SCAL_OFF (NROWS * FSTR)
#define LDS_FLOATS (SCAL_OFF + NROWS * SCAL_STR)   // 13120 floats = 52480 B

typedef __attribute__((ext_vector_type(4))) float f32x4;

static __device__ __forceinline__ float4 ld4(const float* p) {
    return *reinterpret_cast<const float4*>(p);
}

__global__ __launch_bounds__(256, 3)
void tp_valu_v8(const float* __restrict__ x1,
                const float* __restrict__ x2,
                const float* __restrict__ w000,
                const float* __restrict__ w011,
                const float* __restrict__ w101,
                const float* __restrict__ w110,
                const float* __restrict__ w112,
                float* __restrict__ out) {
    __shared__ __align__(16) float lds[LDS_FLOATS];
    float* feat = lds;
    float* scal = lds + SCAL_OFF;

    constexpr float INV3 = 0.57735026918962576f;   // 1/sqrt(3)
    constexpr float INV6 = 0.40824829046386302f;   // 1/sqrt(6)

    const int t   = threadIdx.x;
    const int row = t & 63;                        // staging / store row
    const int q   = t >> 6;                        // wave id
    const int wvu = __builtin_amdgcn_readfirstlane(q);
    const long rbase = (long)blockIdx.x * NROWS;

    const float* x1r = x1 + (rbase + row) * DIM1;
    float* frS = feat + row * FSTR;

    const float4 xr2 = ld4(x2 + (rbase + row) * 4);
    const float s2 = xr2.x, vx = xr2.y, vy = xr2.z, vz = xr2.w;
    if (q == 0) {
        scal[row*SCAL_STR+0] = s2;
        scal[row*SCAL_STR+1] = s2 * INV3;
        scal[row*SCAL_STR+2] = vx * INV3;
        scal[row*SCAL_STR+3] = vy * INV3;
        scal[row*SCAL_STR+4] = vz * INV3;
        scal[row*SCAL_STR+5] = vx * INV6;
        scal[row*SCAL_STR+6] = vy * INV6;
        scal[row*SCAL_STR+7] = vz * INV6;
    }

    // ---------------- stage S: featA = [x1s raw (0..127) | d*INV3 (128..191)] ----------------
    {
        #pragma unroll
        for (int i = 0; i < 8; ++i) {
            float4 v = ld4(x1r + q*32 + 4*i);
            *reinterpret_cast<float4*>(frS + q*32 + 4*i) = v;
        }
        float qf[48];
        #pragma unroll
        for (int c = 0; c < 12; ++c) {
            float4 v = ld4(x1r + 128 + 48*q + 4*c);
            qf[4*c+0]=v.x; qf[4*c+1]=v.y; qf[4*c+2]=v.z; qf[4*c+3]=v.w;
        }
        #pragma unroll
        for (int i = 0; i < 16; ++i) {
            const int u = 16*q + i;
            frS[128 + u] = (qf[3*i]*vx + qf[3*i+1]*vy + qf[3*i+2]*vz) * INV3;
        }
    }
    __syncthreads();

    // compute-phase thread map: 4 rows per thread (quad), col chunk cc
    const int quad = t >> 4;                       // 0..15 -> rows 4*quad..4*quad+3
    const int cc   = t & 15;
    const int r0   = 4 * quad;
    const float* f0 = feat + (r0 + 0) * FSTR;
    const float* f1 = feat + (r0 + 1) * FSTR;
    const float* f2 = feat + (r0 + 2) * FSTR;
    const float* f3 = feat + (r0 + 3) * FSTR;

    #define FMAS8(ACC, W, FOFF)                                              \
      do {                                                                   \
        f32x4 qq[4];                                                         \
        qq[0] = *reinterpret_cast<const f32x4*>(f0 + (FOFF));                \
        qq[1] = *reinterpret_cast<const f32x4*>(f1 + (FOFF));                \
        qq[2] = *reinterpret_cast<const f32x4*>(f2 + (FOFF));                \
        qq[3] = *reinterpret_cast<const f32x4*>(f3 + (FOFF));                \
        _Pragma("unroll")                                                    \
        for (int r_ = 0; r_ < 4; ++r_) {                                     \
          _Pragma("unroll")                                                  \
          for (int dk_ = 0; dk_ < 4; ++dk_) {                                \
            const float fv_ = qq[r_][dk_];                                   \
            const float4 wlo_ = W[2*dk_], whi_ = W[2*dk_+1];                 \
            ACC[r_*8+0] += fv_*wlo_.x;  ACC[r_*8+1] += fv_*wlo_.y;           \
            ACC[r_*8+2] += fv_*wlo_.z;  ACC[r_*8+3] += fv_*wlo_.w;           \
            ACC[r_*8+4] += fv_*whi_.x;  ACC[r_*8+5] += fv_*whi_.y;           \
            ACC[r_*8+6] += fv_*whi_.z;  ACC[r_*8+7] += fv_*whi_.w;           \
          }                                                                  \
        }                                                                    \
      } while (0)

    #define LOADW8(W, BASE, KT)                                              \
      do {                                                                   \
        const float* wp_ = (BASE) + (size_t)(4*(KT))*128;                    \
        _Pragma("unroll")                                                    \
        for (int dk_ = 0; dk_ < 4; ++dk_) {                                  \
          W[2*dk_]   = ld4(wp_ + dk_*128);                                   \
          W[2*dk_+1] = ld4(wp_ + dk_*128 + 4);                               \
        }                                                                    \
      } while (0)

    #define FMAS4(ACC, W, FOFF)                                              \
      do {                                                                   \
        f32x4 qq[4];                                                         \
        qq[0] = *reinterpret_cast<const f32x4*>(f0 + (FOFF));                \
        qq[1] = *reinterpret_cast<const f32x4*>(f1 + (FOFF));                \
        qq[2] = *reinterpret_cast<const f32x4*>(f2 + (FOFF));                \
        qq[3] = *reinterpret_cast<const f32x4*>(f3 + (FOFF));                \
        _Pragma("unroll")                                                    \
        for (int r_ = 0; r_ < 4; ++r_) {                                     \
          _Pragma("unroll")                                                  \
          for (int dk_ = 0; dk_ < 4; ++dk_) {                                \
            const float fv_ = qq[r_][dk_];                                   \
            const float4 w_ = W[dk_];                                        \
            ACC[r_*4+0] += fv_*w_.x;  ACC[r_*4+1] += fv_*w_.y;               \
            ACC[r_*4+2] += fv_*w_.z;  ACC[r_*4+3] += fv_*w_.w;               \
          }                                                                  \
        }                                                                    \
      } while (0)

    #define LOADW4(W, BASE, KT)                                              \
      do {                                                                   \
        const float* wp_ = (BASE) + (size_t)(4*(KT))*64;                     \
        _Pragma("unroll")                                                    \
        for (int dk_ = 0; dk_ < 4; ++dk_) W[dk_] = ld4(wp_ + dk_*64);        \
      } while (0)

    // ---------------- P1: out0 accs (A: K=128 w000, D: K=64 w110), cols 8*cc ----------------
    const int c8 = cc * 8;
    float accA[32], accD[32];
    #pragma unroll
    for (int i = 0; i < 32; ++i) { accA[i] = 0.f; accD[i] = 0.f; }
    {
        const float* wb = w000 + c8;
        float4 wA[8], wB[8];
        LOADW8(wA, wb, 0);
        for (int kp = 0; kp < 16; ++kp) {
            const int ktA = 2*kp;
            LOADW8(wB, wb, ktA+1);
            FMAS8(accA, wA, 4*ktA);
            LOADW8(wA, wb, (kp < 15) ? ktA+2 : 30);
            FMAS8(accA, wB, 4*(ktA+1));
        }
    }
    {
        const float* wb = w110 + c8;
        float4 wA[8], wB[8];
        LOADW8(wA, wb, 0);
        for (int kp = 0; kp < 8; ++kp) {
            const int ktA = 2*kp;
            LOADW8(wB, wb, ktA+1);
            FMAS8(accD, wA, 128 + 4*ktA);
            LOADW8(wA, wb, (kp < 7) ? ktA+2 : 14);
            FMAS8(accD, wB, 128 + 4*(ktA+1));
        }
    }

    // ---------------- P2: out1 b-part (K=128 w011), cols 4*cc ----------------
    const int c4 = cc * 4;
    float accB[16];
    #pragma unroll
    for (int i = 0; i < 16; ++i) accB[i] = 0.f;
    {
        const float* wb = w011 + c4;
        float4 wA[4], wB[4];
        LOADW4(wA, wb, 0);
        for (int kp = 0; kp < 16; ++kp) {
            const int ktA = 2*kp;
            LOADW4(wB, wb, ktA+1);
            FMAS4(accB, wA, 4*ktA);
            LOADW4(wA, wb, (kp < 15) ? ktA+2 : 30);
            FMAS4(accB, wB, 4*(ktA+1));
        }
    }
    __syncthreads();   // featA reads done

    // ---------------- stage out0 -> LDS (combine in place), then contiguous store ----------------
    #pragma unroll
    for (int r = 0; r < 4; ++r) {
        const float s2r = scal[(r0 + r)*SCAL_STR + 0];
        float* dst = feat + (r0 + r) * FSTR + c8;
        f32x4 v0, v1;
        #pragma unroll
        for (int cj = 0; cj < 4; ++cj) {
            v0[cj] = s2r*accA[r*8+cj]   + accD[r*8+cj];
            v1[cj] = s2r*accA[r*8+4+cj] + accD[r*8+4+cj];
        }
        *reinterpret_cast<f32x4*>(dst)     = v0;
        *reinterpret_cast<f32x4*>(dst + 4) = v1;
    }
    __syncthreads();
    {   // global store out0: lane=row, 128 B contiguous per thread
        const float* srow = feat + row * FSTR + 32*q;
        float* orow = out + (rbase + row)*OUTD + 32*q;
        #pragma unroll
        for (int i = 0; i < 8; ++i)
            *reinterpret_cast<float4*>(orow + 4*i) =
                *reinterpret_cast<const float4*>(srow + 4*i);
    }
    __syncthreads();   // out0 LDS reads done before featT overwrite

    // ---------------- stage T: featT = [v0 | v1 | v2] ----------------
    {
        float qf[48];
        #pragma unroll
        for (int c = 0; c < 12; ++c) {
            float4 v = ld4(x1r + 128 + 48*q + 4*c);
            qf[4*c+0]=v.x; qf[4*c+1]=v.y; qf[4*c+2]=v.z; qf[4*c+3]=v.w;
        }
        #pragma unroll
        for (int i = 0; i < 16; ++i) {
            const int u = 16*q + i;
            frS[u]       = qf[3*i+0];
            frS[64 + u]  = qf[3*i+1];
            frS[128 + u] = qf[3*i+2];
        }
    }
    __syncthreads();

    // ---------------- P3: out1 e-part (K=64 w101, 3 comps), quad map ----------------
    float accE0[16], accE1[16], accE2[16];
    #pragma unroll
    for (int i = 0; i < 16; ++i) { accE0[i]=0.f; accE1[i]=0.f; accE2[i]=0.f; }
    {
        const float* wb = w101 + c4;
        float4 wA[4], wB[4];
        LOADW4(wA, wb, 0);
        for (int up = 0; up < 8; ++up) {
            const int utA = 2*up;
            LOADW4(wB, wb, utA+1);
            FMAS4(accE0, wA, 4*utA);
            FMAS4(accE1, wA, 64 + 4*utA);
            FMAS4(accE2, wA, 128 + 4*utA);
            LOADW4(wA, wb, (up < 7) ? utA+2 : 14);
            FMAS4(accE0, wB, 4*(utA+1));
            FMAS4(accE1, wB, 64 + 4*(utA+1));
            FMAS4(accE2, wB, 128 + 4*(utA+1));
        }
    }

    // ---------------- P4: out2 G-part (K=64 w112, 3 comps), lane=row map ----------------
    float accG0[8], accG1[8], accG2[8];
    #pragma unroll
    for (int i = 0; i < 8; ++i) { accG0[i]=0.f; accG1[i]=0.f; accG2[i]=0.f; }
    {
        const float* frC = feat + row * FSTR;
        const int wb = wvu * 8;
        #pragma unroll 2
        for (int ut = 0; ut < 16; ++ut) {
            f32x4 g0 = *reinterpret_cast<const f32x4*>(frC + 4*ut);
            f32x4 g1 = *reinterpret_cast<const f32x4*>(frC + 64 + 4*ut);
            f32x4 g2 = *reinterpret_cast<const f32x4*>(frC + 128 + 4*ut);
            #pragma unroll
            for (int du = 0; du < 4; ++du) {
                const float* wp = w112 + (4*ut+du)*32 + wb;
                float4 wa = ld4(wp);
                float4 wb4 = ld4(wp + 4);
                const float wvals[8] = {wa.x, wa.y, wa.z, wa.w, wb4.x, wb4.y, wb4.z, wb4.w};
                #pragma unroll
                for (int wl = 0; wl < 8; ++wl) {
                    accG0[wl] += g0[du] * wvals[wl];
                    accG1[wl] += g1[du] * wvals[wl];
                    accG2[wl] += g2[du] * wvals[wl];
                }
            }
        }
    }
    __syncthreads();   // featT reads done

    // ---------------- stage out1 -> LDS (combine), then contiguous store ----------------
    #pragma unroll
    for (int r = 0; r < 4; ++r) {
        const int rw = r0 + r;
        const float s2I = scal[rw*SCAL_STR+1];
        const float vxI = scal[rw*SCAL_STR+2];
        const float vyI = scal[rw*SCAL_STR+3];
        const float vzI = scal[rw*SCAL_STR+4];
        float vals[12];
        #pragma unroll
        for (int cj = 0; cj < 4; ++cj) {
            const float b = accB[r*4+cj];
            vals[3*cj+0] = vxI*b + s2I*accE0[r*4+cj];
            vals[3*cj+1] = vyI*b + s2I*accE1[r*4+cj];
            vals[3*cj+2] = vzI*b + s2I*accE2[r*4+cj];
        }
        float* dst = feat + rw * FSTR + 12*cc;
        *reinterpret_cast<f32x4*>(dst)     = *reinterpret_cast<const f32x4*>(vals);
        *reinterpret_cast<f32x4*>(dst + 4) = *reinterpret_cast<const f32x4*>(vals + 4);
        *reinterpret_cast<f32x4*>(dst + 8) = *reinterpret_cast<const f32x4*>(vals + 8);
    }
    __syncthreads();
    {   // global store out1: lane=row, 192 B contiguous per thread
        const float* srow = feat + row * FSTR + 48*q;
        float* orow = out + (rbase + row)*OUTD + 128 + 48*q;
        #pragma unroll
        for (int i = 0; i < 12; ++i)
            *reinterpret_cast<float4*>(orow + 4*i) =
                *reinterpret_cast<const float4*>(srow + 4*i);
    }

    // ---------------- out2 epilogue: cross(G, v)*INV6, direct store (R6-proven pattern) ----------------
    {
        const float v6x = scal[row*SCAL_STR+5];
        const float v6y = scal[row*SCAL_STR+6];
        const float v6z = scal[row*SCAL_STR+7];
        float ov[24];
        #pragma unroll
        for (int wl = 0; wl < 8; ++wl) {
            ov[3*wl+0] = accG1[wl]*v6z - accG2[wl]*v6y;
            ov[3*wl+1] = accG2[wl]*v6x - accG0[wl]*v6z;
            ov[3*wl+2] = accG0[wl]*v6y - accG1[wl]*v6x;
        }
        float* orow = out + (rbase + row)*OUTD + 320 + 24*wvu;
        #pragma unroll
        for (int qq = 0; qq < 6; ++qq)
            *reinterpret_cast<float4*>(orow + 4*qq) =
                make_float4(ov[4*qq], ov[4*qq+1], ov[4*qq+2], ov[4*qq+3]);
    }

    #undef FMAS8
    #undef FMAS4
    #undef LOADW8
    #undef LOADW4
}

extern "C" void kernel_launch(void* const* d_in, const int* in_sizes, int n_in,
                              void* d_out, int out_size, void* d_ws, size_t ws_size,
                              hipStream_t stream) {
    const float* x1   = (const float*)d_in[0];
    const float* x2   = (const float*)d_in[1];
    const float* w000 = (const float*)d_in[2];
    const float* w011 = (const float*)d_in[3];
    const float* w101 = (const float*)d_in[4];
    const float* w110 = (const float*)d_in[5];
    const float* w112 = (const float*)d_in[6];
    // d_in[7] = w3j111 — folded analytically (cross with v2, scaled 1/sqrt6).
    float* out = (float*)d_out;

    tp_valu_v8<<<dim3(NBLK), dim3(256), 0, stream>>>(
        x1, x2, w000, w011, w101, w110, w112, out);
}

// Round 9
// 720.580 us; speedup vs baseline: 1.8579x; 1.8579x over previous
//
#include <hip/hip_runtime.h>

#define M_ROWS 200000
#define NROWS  64            // rows per block
#define NBLK   3125          // 200000 / 64, exact
#define DIM1   320
#define OUTD   416
#define FSTR   196           // feat row stride (floats)

#define SCAL_STR 9
#define SCAL_OFF (NROWS * FSTR)
#define LDS_FLOATS (SCAL_OFF + NROWS * SCAL_STR)   // 13120 floats = 52480 B

typedef __attribute__((ext_vector_type(4))) float f32x4;

static __device__ __forceinline__ float4 ld4(const float* p) {
    return *reinterpret_cast<const float4*>(p);
}

// NOTE: (256,2) NOT (256,3): with min-waves=3 the allocator targeted 84 VGPR and
// spilled all accumulators (R8: 3.7 GB scratch traffic, 1.34 ms). (256,2) -> 128+ VGPR, no spill.
__global__ __launch_bounds__(256, 2)
void tp_valu_v9(const float* __restrict__ x1,
                const float* __restrict__ x2,
                const float* __restrict__ w000,
                const float* __restrict__ w011,
                const float* __restrict__ w101,
                const float* __restrict__ w110,
                const float* __restrict__ w112,
                float* __restrict__ out) {
    __shared__ __align__(16) float lds[LDS_FLOATS];
    float* feat = lds;
    float* scal = lds + SCAL_OFF;

    constexpr float INV3 = 0.57735026918962576f;   // 1/sqrt(3)
    constexpr float INV6 = 0.40824829046386302f;   // 1/sqrt(6)

    const int t   = threadIdx.x;
    const int row = t & 63;                        // staging / store row
    const int q   = t >> 6;                        // wave id
    const int wvu = __builtin_amdgcn_readfirstlane(q);
    const long rbase = (long)blockIdx.x * NROWS;

    const float* x1r = x1 + (rbase + row) * DIM1;
    float* frS = feat + row * FSTR;

    const float4 xr2 = ld4(x2 + (rbase + row) * 4);
    const float s2 = xr2.x, vx = xr2.y, vy = xr2.z, vz = xr2.w;
    if (q == 0) {
        scal[row*SCAL_STR+0] = s2;
        scal[row*SCAL_STR+1] = s2 * INV3;
        scal[row*SCAL_STR+2] = vx * INV3;
        scal[row*SCAL_STR+3] = vy * INV3;
        scal[row*SCAL_STR+4] = vz * INV3;
        scal[row*SCAL_STR+5] = vx * INV6;
        scal[row*SCAL_STR+6] = vy * INV6;
        scal[row*SCAL_STR+7] = vz * INV6;
    }

    // ---------------- stage S: featA = [x1s raw (0..127) | d*INV3 (128..191)] ----------------
    {
        #pragma unroll
        for (int i = 0; i < 8; ++i) {
            float4 v = ld4(x1r + q*32 + 4*i);
            *reinterpret_cast<float4*>(frS + q*32 + 4*i) = v;
        }
        float qf[48];
        #pragma unroll
        for (int c = 0; c < 12; ++c) {
            float4 v = ld4(x1r + 128 + 48*q + 4*c);
            qf[4*c+0]=v.x; qf[4*c+1]=v.y; qf[4*c+2]=v.z; qf[4*c+3]=v.w;
        }
        #pragma unroll
        for (int i = 0; i < 16; ++i) {
            const int u = 16*q + i;
            frS[128 + u] = (qf[3*i]*vx + qf[3*i+1]*vy + qf[3*i+2]*vz) * INV3;
        }
    }
    __syncthreads();

    // compute-phase thread map: 4 rows per thread (quad), col chunk cc
    const int quad = t >> 4;                       // 0..15 -> rows 4*quad..4*quad+3
    const int cc   = t & 15;
    const int r0   = 4 * quad;
    const float* f0 = feat + (r0 + 0) * FSTR;
    const float* f1 = feat + (r0 + 1) * FSTR;
    const float* f2 = feat + (r0 + 2) * FSTR;
    const float* f3 = feat + (r0 + 3) * FSTR;

    #define FMAS8(ACC, W, FOFF)                                              \
      do {                                                                   \
        f32x4 qq[4];                                                         \
        qq[0] = *reinterpret_cast<const f32x4*>(f0 + (FOFF));                \
        qq[1] = *reinterpret_cast<const f32x4*>(f1 + (FOFF));                \
        qq[2] = *reinterpret_cast<const f32x4*>(f2 + (FOFF));                \
        qq[3] = *reinterpret_cast<const f32x4*>(f3 + (FOFF));                \
        _Pragma("unroll")                                                    \
        for (int r_ = 0; r_ < 4; ++r_) {                                     \
          _Pragma("unroll")                                                  \
          for (int dk_ = 0; dk_ < 4; ++dk_) {                                \
            const float fv_ = qq[r_][dk_];                                   \
            const float4 wlo_ = W[2*dk_], whi_ = W[2*dk_+1];                 \
            ACC[r_*8+0] += fv_*wlo_.x;  ACC[r_*8+1] += fv_*wlo_.y;           \
            ACC[r_*8+2] += fv_*wlo_.z;  ACC[r_*8+3] += fv_*wlo_.w;           \
            ACC[r_*8+4] += fv_*whi_.x;  ACC[r_*8+5] += fv_*whi_.y;           \
            ACC[r_*8+6] += fv_*whi_.z;  ACC[r_*8+7] += fv_*whi_.w;           \
          }                                                                  \
        }                                                                    \
      } while (0)

    #define LOADW8(W, BASE, KT)                                              \
      do {                                                                   \
        const float* wp_ = (BASE) + (size_t)(4*(KT))*128;                    \
        _Pragma("unroll")                                                    \
        for (int dk_ = 0; dk_ < 4; ++dk_) {                                  \
          W[2*dk_]   = ld4(wp_ + dk_*128);                                   \
          W[2*dk_+1] = ld4(wp_ + dk_*128 + 4);                               \
        }                                                                    \
      } while (0)

    #define FMAS4(ACC, W, FOFF)                                              \
      do {                                                                   \
        f32x4 qq[4];                                                         \
        qq[0] = *reinterpret_cast<const f32x4*>(f0 + (FOFF));                \
        qq[1] = *reinterpret_cast<const f32x4*>(f1 + (FOFF));                \
        qq[2] = *reinterpret_cast<const f32x4*>(f2 + (FOFF));                \
        qq[3] = *reinterpret_cast<const f32x4*>(f3 + (FOFF));                \
        _Pragma("unroll")                                                    \
        for (int r_ = 0; r_ < 4; ++r_) {                                     \
          _Pragma("unroll")                                                  \
          for (int dk_ = 0; dk_ < 4; ++dk_) {                                \
            const float fv_ = qq[r_][dk_];                                   \
            const float4 w_ = W[dk_];                                        \
            ACC[r_*4+0] += fv_*w_.x;  ACC[r_*4+1] += fv_*w_.y;               \
            ACC[r_*4+2] += fv_*w_.z;  ACC[r_*4+3] += fv_*w_.w;               \
          }                                                                  \
        }                                                                    \
      } while (0)

    #define LOADW4(W, BASE, KT)                                              \
      do {                                                                   \
        const float* wp_ = (BASE) + (size_t)(4*(KT))*64;                     \
        _Pragma("unroll")                                                    \
        for (int dk_ = 0; dk_ < 4; ++dk_) W[dk_] = ld4(wp_ + dk_*64);        \
      } while (0)

    // ---------------- P1: out0 accs (A: K=128 w000, D: K=64 w110), cols 8*cc ----------------
    const int c8 = cc * 8;
    float accA[32], accD[32];
    #pragma unroll
    for (int i = 0; i < 32; ++i) { accA[i] = 0.f; accD[i] = 0.f; }
    {
        const float* wb = w000 + c8;
        float4 wA[8], wB[8];
        LOADW8(wA, wb, 0);
        for (int kp = 0; kp < 16; ++kp) {
            const int ktA = 2*kp;
            LOADW8(wB, wb, ktA+1);
            FMAS8(accA, wA, 4*ktA);
            LOADW8(wA, wb, (kp < 15) ? ktA+2 : 30);
            FMAS8(accA, wB, 4*(ktA+1));
        }
    }
    {
        const float* wb = w110 + c8;
        float4 wA[8], wB[8];
        LOADW8(wA, wb, 0);
        for (int kp = 0; kp < 8; ++kp) {
            const int ktA = 2*kp;
            LOADW8(wB, wb, ktA+1);
            FMAS8(accD, wA, 128 + 4*ktA);
            LOADW8(wA, wb, (kp < 7) ? ktA+2 : 14);
            FMAS8(accD, wB, 128 + 4*(ktA+1));
        }
    }

    // ---------------- P2: out1 b-part (K=128 w011), cols 4*cc ----------------
    const int c4 = cc * 4;
    float accB[16];
    #pragma unroll
    for (int i = 0; i < 16; ++i) accB[i] = 0.f;
    {
        const float* wb = w011 + c4;
        float4 wA[4], wB[4];
        LOADW4(wA, wb, 0);
        for (int kp = 0; kp < 16; ++kp) {
            const int ktA = 2*kp;
            LOADW4(wB, wb, ktA+1);
            FMAS4(accB, wA, 4*ktA);
            LOADW4(wA, wb, (kp < 15) ? ktA+2 : 30);
            FMAS4(accB, wB, 4*(ktA+1));
        }
    }
    __syncthreads();   // featA reads done

    // ---------------- stage out0 -> LDS (combine in place), then contiguous store ----------------
    #pragma unroll
    for (int r = 0; r < 4; ++r) {
        const float s2r = scal[(r0 + r)*SCAL_STR + 0];
        float* dst = feat + (r0 + r) * FSTR + c8;
        f32x4 v0, v1;
        #pragma unroll
        for (int cj = 0; cj < 4; ++cj) {
            v0[cj] = s2r*accA[r*8+cj]   + accD[r*8+cj];
            v1[cj] = s2r*accA[r*8+4+cj] + accD[r*8+4+cj];
        }
        *reinterpret_cast<f32x4*>(dst)     = v0;
        *reinterpret_cast<f32x4*>(dst + 4) = v1;
    }
    __syncthreads();
    {   // global store out0: lane=row, 128 B contiguous per thread
        const float* srow = feat + row * FSTR + 32*q;
        float* orow = out + (rbase + row)*OUTD + 32*q;
        #pragma unroll
        for (int i = 0; i < 8; ++i)
            *reinterpret_cast<float4*>(orow + 4*i) =
                *reinterpret_cast<const float4*>(srow + 4*i);
    }
    __syncthreads();   // out0 LDS reads done before featT overwrite

    // ---------------- stage T: featT = [v0 | v1 | v2] ----------------
    {
        float qf[48];
        #pragma unroll
        for (int c = 0; c < 12; ++c) {
            float4 v = ld4(x1r + 128 + 48*q + 4*c);
            qf[4*c+0]=v.x; qf[4*c+1]=v.y; qf[4*c+2]=v.z; qf[4*c+3]=v.w;
        }
        #pragma unroll
        for (int i = 0; i < 16; ++i) {
            const int u = 16*q + i;
            frS[u]       = qf[3*i+0];
            frS[64 + u]  = qf[3*i+1];
            frS[128 + u] = qf[3*i+2];
        }
    }
    __syncthreads();

    // ---------------- P3: out1 e-part (K=64 w101, 3 comps), quad map ----------------
    float accE0[16], accE1[16], accE2[16];
    #pragma unroll
    for (int i = 0; i < 16; ++i) { accE0[i]=0.f; accE1[i]=0.f; accE2[i]=0.f; }
    {
        const float* wb = w101 + c4;
        float4 wA[4], wB[4];
        LOADW4(wA, wb, 0);
        for (int up = 0; up < 8; ++up) {
            const int utA = 2*up;
            LOADW4(wB, wb, utA+1);
            FMAS4(accE0, wA, 4*utA);
            FMAS4(accE1, wA, 64 + 4*utA);
            FMAS4(accE2, wA, 128 + 4*utA);
            LOADW4(wA, wb, (up < 7) ? utA+2 : 14);
            FMAS4(accE0, wB, 4*(utA+1));
            FMAS4(accE1, wB, 64 + 4*(utA+1));
            FMAS4(accE2, wB, 128 + 4*(utA+1));
        }
    }

    // ---------------- P4: out2 G-part (K=64 w112, 3 comps), lane=row map ----------------
    float accG0[8], accG1[8], accG2[8];
    #pragma unroll
    for (int i = 0; i < 8; ++i) { accG0[i]=0.f; accG1[i]=0.f; accG2[i]=0.f; }
    {
        const float* frC = feat + row * FSTR;
        const int wb = wvu * 8;
        #pragma unroll 2
        for (int ut = 0; ut < 16; ++ut) {
            f32x4 g0 = *reinterpret_cast<const f32x4*>(frC + 4*ut);
            f32x4 g1 = *reinterpret_cast<const f32x4*>(frC + 64 + 4*ut);
            f32x4 g2 = *reinterpret_cast<const f32x4*>(frC + 128 + 4*ut);
            #pragma unroll
            for (int du = 0; du < 4; ++du) {
                const float* wp = w112 + (4*ut+du)*32 + wb;
                float4 wa = ld4(wp);
                float4 wb4 = ld4(wp + 4);
                const float wvals[8] = {wa.x, wa.y, wa.z, wa.w, wb4.x, wb4.y, wb4.z, wb4.w};
                #pragma unroll
                for (int wl = 0; wl < 8; ++wl) {
                    accG0[wl] += g0[du] * wvals[wl];
                    accG1[wl] += g1[du] * wvals[wl];
                    accG2[wl] += g2[du] * wvals[wl];
                }
            }
        }
    }
    __syncthreads();   // featT reads done

    // ---------------- stage out1 -> LDS (combine), then contiguous store ----------------
    #pragma unroll
    for (int r = 0; r < 4; ++r) {
        const int rw = r0 + r;
        const float s2I = scal[rw*SCAL_STR+1];
        const float vxI = scal[rw*SCAL_STR+2];
        const float vyI = scal[rw*SCAL_STR+3];
        const float vzI = scal[rw*SCAL_STR+4];
        float vals[12];
        #pragma unroll
        for (int cj = 0; cj < 4; ++cj) {
            const float b = accB[r*4+cj];
            vals[3*cj+0] = vxI*b + s2I*accE0[r*4+cj];
            vals[3*cj+1] = vyI*b + s2I*accE1[r*4+cj];
            vals[3*cj+2] = vzI*b + s2I*accE2[r*4+cj];
        }
        float* dst = feat + rw * FSTR + 12*cc;
        *reinterpret_cast<f32x4*>(dst)     = *reinterpret_cast<const f32x4*>(vals);
        *reinterpret_cast<f32x4*>(dst + 4) = *reinterpret_cast<const f32x4*>(vals + 4);
        *reinterpret_cast<f32x4*>(dst + 8) = *reinterpret_cast<const f32x4*>(vals + 8);
    }
    __syncthreads();
    {   // global store out1: lane=row, 192 B contiguous per thread
        const float* srow = feat + row * FSTR + 48*q;
        float* orow = out + (rbase + row)*OUTD + 128 + 48*q;
        #pragma unroll
        for (int i = 0; i < 12; ++i)
            *reinterpret_cast<float4*>(orow + 4*i) =
                *reinterpret_cast<const float4*>(srow + 4*i);
    }

    // ---------------- out2 epilogue: cross(G, v)*INV6, direct store ----------------
    {
        const float v6x = scal[row*SCAL_STR+5];
        const float v6y = scal[row*SCAL_STR+6];
        const float v6z = scal[row*SCAL_STR+7];
        float ov[24];
        #pragma unroll
        for (int wl = 0; wl < 8; ++wl) {
            ov[3*wl+0] = accG1[wl]*v6z - accG2[wl]*v6y;
            ov[3*wl+1] = accG2[wl]*v6x - accG0[wl]*v6z;
            ov[3*wl+2] = accG0[wl]*v6y - accG1[wl]*v6x;
        }
        float* orow = out + (rbase + row)*OUTD + 320 + 24*wvu;
        #pragma unroll
        for (int qq = 0; qq < 6; ++qq)
            *reinterpret_cast<float4*>(orow + 4*qq) =
                make_float4(ov[4*qq], ov[4*qq+1], ov[4*qq+2], ov[4*qq+3]);
    }

    #undef FMAS8
    #undef FMAS4
    #undef LOADW8
    #undef LOADW4
}

extern "C" void kernel_launch(void* const* d_in, const int* in_sizes, int n_in,
                              void* d_out, int out_size, void* d_ws, size_t ws_size,
                              hipStream_t stream) {
    const float* x1   = (const float*)d_in[0];
    const float* x2   = (const float*)d_in[1];
    const float* w000 = (const float*)d_in[2];
    const float* w011 = (const float*)d_in[3];
    const float* w101 = (const float*)d_in[4];
    const float* w110 = (const float*)d_in[5];
    const float* w112 = (const float*)d_in[6];
    // d_in[7] = w3j111 — folded analytically (cross with v2, scaled 1/sqrt6).
    float* out = (float*)d_out;

    tp_valu_v9<<<dim3(NBLK), dim3(256), 0, stream>>>(
        x1, x2, w000, w011, w101, w110, w112, out);
}

// Round 10
// 430.862 us; speedup vs baseline: 3.1072x; 1.6724x over previous
//
#include <hip/hip_runtime.h>

#define M_ROWS 200000
#define NROWS  64            // rows per block
#define NBLK   3125          // 200000 / 64, exact
#define DIM1   320
#define OUTD   416
#define FSTR   196           // feat row stride (floats)

#define SCAL_STR 9
#define SCAL_OFF (NROWS * FSTR)
#define LDS_FLOATS (SCAL_OFF + NROWS * SCAL_STR)   // 13120 floats = 52480 B

typedef __attribute__((ext_vector_type(4))) float f32x4;

static __device__ __forceinline__ float4 ld4(const float* p) {
    return *reinterpret_cast<const float4*>(p);
}

// launch_bounds(256,2): (256,3) made the allocator target 84 VGPR -> total spill (R8).
// At 128 VGPR the kernel must have live-set < ~115: R7/R9 held 128+ live in P1 and
// spilled (R9: +0.9GB write, +0.4GB fetch of scratch traffic). This version keeps
// peak live ~100 (merged out0 acc, 2-k-row weight dbuf, hoisted P3 weights).
__global__ __launch_bounds__(256, 2)
void tp_valu_v10(const float* __restrict__ x1,
                 const float* __restrict__ x2,
                 const float* __restrict__ w000,
                 const float* __restrict__ w011,
                 const float* __restrict__ w101,
                 const float* __restrict__ w110,
                 const float* __restrict__ w112,
                 float* __restrict__ out) {
    __shared__ __align__(16) float lds[LDS_FLOATS];
    float* feat = lds;
    float* scal = lds + SCAL_OFF;

    constexpr float INV3 = 0.57735026918962576f;   // 1/sqrt(3)
    constexpr float INV6 = 0.40824829046386302f;   // 1/sqrt(6)

    const int t   = threadIdx.x;
    const int row = t & 63;                        // staging / store row
    const int q   = t >> 6;                        // wave id
    const int wvu = __builtin_amdgcn_readfirstlane(q);
    const long rbase = (long)blockIdx.x * NROWS;

    const float* x1r = x1 + (rbase + row) * DIM1;
    float* frS = feat + row * FSTR;

    const float4 xr2 = ld4(x2 + (rbase + row) * 4);
    const float s2 = xr2.x, vx = xr2.y, vy = xr2.z, vz = xr2.w;
    if (q == 0) {
        scal[row*SCAL_STR+0] = s2;
        scal[row*SCAL_STR+1] = s2 * INV3;
        scal[row*SCAL_STR+2] = vx * INV3;
        scal[row*SCAL_STR+3] = vy * INV3;
        scal[row*SCAL_STR+4] = vz * INV3;
        scal[row*SCAL_STR+5] = vx * INV6;
        scal[row*SCAL_STR+6] = vy * INV6;
        scal[row*SCAL_STR+7] = vz * INV6;
    }

    // ---------------- stage S: featA = [x1s raw (0..127) | d*INV3 (128..191)] ----------------
    {
        #pragma unroll
        for (int i = 0; i < 8; ++i) {
            float4 v = ld4(x1r + q*32 + 4*i);
            *reinterpret_cast<float4*>(frS + q*32 + 4*i) = v;
        }
        float qf[48];
        #pragma unroll
        for (int c = 0; c < 12; ++c) {
            float4 v = ld4(x1r + 128 + 48*q + 4*c);
            qf[4*c+0]=v.x; qf[4*c+1]=v.y; qf[4*c+2]=v.z; qf[4*c+3]=v.w;
        }
        #pragma unroll
        for (int i = 0; i < 16; ++i) {
            const int u = 16*q + i;
            frS[128 + u] = (qf[3*i]*vx + qf[3*i+1]*vy + qf[3*i+2]*vz) * INV3;
        }
    }
    __syncthreads();

    // compute-phase thread map: 4 rows per thread (quad), col chunk cc
    const int quad = t >> 4;                       // 0..15 -> rows 4*quad..4*quad+3
    const int cc   = t & 15;
    const int r0   = 4 * quad;
    const float* f0 = feat + (r0 + 0) * FSTR;
    const float* f1 = feat + (r0 + 1) * FSTR;
    const float* f2 = feat + (r0 + 2) * FSTR;
    const float* f3 = feat + (r0 + 3) * FSTR;

    // 2-k-row x 8-col weight chunk (4 float4 = 16 regs per buffer)
    #define LOADW8H(W, BASE, K2)                                             \
      do {                                                                   \
        const float* wp_ = (BASE) + (size_t)(2*(K2))*128;                    \
        W[0] = ld4(wp_);        W[1] = ld4(wp_ + 4);                         \
        W[2] = ld4(wp_ + 128);  W[3] = ld4(wp_ + 132);                       \
      } while (0)

    // consume half H (k-pair) of a 4-k feature block QQ
    #define FMAS8H(ACC, W, QQ, H)                                            \
      do {                                                                   \
        _Pragma("unroll")                                                    \
        for (int r_ = 0; r_ < 4; ++r_) {                                     \
          const float a_ = QQ[r_][2*(H)], b_ = QQ[r_][2*(H)+1];              \
          ACC[r_*8+0] += a_*W[0].x;  ACC[r_*8+1] += a_*W[0].y;               \
          ACC[r_*8+2] += a_*W[0].z;  ACC[r_*8+3] += a_*W[0].w;               \
          ACC[r_*8+4] += a_*W[1].x;  ACC[r_*8+5] += a_*W[1].y;               \
          ACC[r_*8+6] += a_*W[1].z;  ACC[r_*8+7] += a_*W[1].w;               \
          ACC[r_*8+0] += b_*W[2].x;  ACC[r_*8+1] += b_*W[2].y;               \
          ACC[r_*8+2] += b_*W[2].z;  ACC[r_*8+3] += b_*W[2].w;               \
          ACC[r_*8+4] += b_*W[3].x;  ACC[r_*8+5] += b_*W[3].y;               \
          ACC[r_*8+6] += b_*W[3].z;  ACC[r_*8+7] += b_*W[3].w;               \
        }                                                                    \
      } while (0)

    // 2-k-row x 4-col weight chunk (2 float4 = 8 regs per buffer)
    #define LOADW4H(W, BASE, K2)                                             \
      do {                                                                   \
        const float* wp_ = (BASE) + (size_t)(2*(K2))*64;                     \
        W[0] = ld4(wp_);  W[1] = ld4(wp_ + 64);                              \
      } while (0)

    #define FMAS4H(ACC, W, QQ, H)                                            \
      do {                                                                   \
        _Pragma("unroll")                                                    \
        for (int r_ = 0; r_ < 4; ++r_) {                                     \
          const float a_ = QQ[r_][2*(H)], b_ = QQ[r_][2*(H)+1];              \
          ACC[r_*4+0] += a_*W[0].x;  ACC[r_*4+1] += a_*W[0].y;               \
          ACC[r_*4+2] += a_*W[0].z;  ACC[r_*4+3] += a_*W[0].w;               \
          ACC[r_*4+0] += b_*W[1].x;  ACC[r_*4+1] += b_*W[1].y;               \
          ACC[r_*4+2] += b_*W[1].z;  ACC[r_*4+3] += b_*W[1].w;               \
        }                                                                    \
      } while (0)

    // full 4-k FMA vs a hoisted 4x4 weight block (P3)
    #define FMAS4(ACC, W, FOFF)                                              \
      do {                                                                   \
        f32x4 qq_[4];                                                        \
        qq_[0] = *reinterpret_cast<const f32x4*>(f0 + (FOFF));               \
        qq_[1] = *reinterpret_cast<const f32x4*>(f1 + (FOFF));               \
        qq_[2] = *reinterpret_cast<const f32x4*>(f2 + (FOFF));               \
        qq_[3] = *reinterpret_cast<const f32x4*>(f3 + (FOFF));               \
        _Pragma("unroll")                                                    \
        for (int r_ = 0; r_ < 4; ++r_) {                                     \
          _Pragma("unroll")                                                  \
          for (int dk_ = 0; dk_ < 4; ++dk_) {                                \
            const float fv_ = qq_[r_][dk_];                                  \
            ACC[r_*4+0] += fv_*W[dk_].x;  ACC[r_*4+1] += fv_*W[dk_].y;       \
            ACC[r_*4+2] += fv_*W[dk_].z;  ACC[r_*4+3] += fv_*W[dk_].w;       \
          }                                                                  \
        }                                                                    \
      } while (0)

    // ---------------- P1: out0 = s2*(x1s@W000) + d@W110, cols 8*cc, merged acc ----------------
    const int c8 = cc * 8;
    float acc0[32];
    #pragma unroll
    for (int i = 0; i < 32; ++i) acc0[i] = 0.f;
    {   // A-part: w000, K=128
        const float* wb = w000 + c8;
        float4 wA[4], wB[4];
        LOADW8H(wA, wb, 0);
        #pragma unroll 1
        for (int k4 = 0; k4 < 32; ++k4) {
            f32x4 qq[4];
            qq[0] = *reinterpret_cast<const f32x4*>(f0 + 4*k4);
            qq[1] = *reinterpret_cast<const f32x4*>(f1 + 4*k4);
            qq[2] = *reinterpret_cast<const f32x4*>(f2 + 4*k4);
            qq[3] = *reinterpret_cast<const f32x4*>(f3 + 4*k4);
            LOADW8H(wB, wb, 2*k4+1);
            FMAS8H(acc0, wA, qq, 0);
            LOADW8H(wA, wb, (k4 < 31) ? (2*k4+2) : 0);
            FMAS8H(acc0, wB, qq, 1);
        }
    }
    // scale by per-row s2, then accumulate D-part into the SAME registers
    #pragma unroll
    for (int r = 0; r < 4; ++r) {
        const float s2r = scal[(r0 + r)*SCAL_STR + 0];
        #pragma unroll
        for (int c = 0; c < 8; ++c) acc0[r*8+c] *= s2r;
    }
    {   // D-part: w110, K=64, features at 128+
        const float* wb = w110 + c8;
        float4 wA[4], wB[4];
        LOADW8H(wA, wb, 0);
        #pragma unroll 1
        for (int k4 = 0; k4 < 16; ++k4) {
            f32x4 qq[4];
            qq[0] = *reinterpret_cast<const f32x4*>(f0 + 128 + 4*k4);
            qq[1] = *reinterpret_cast<const f32x4*>(f1 + 128 + 4*k4);
            qq[2] = *reinterpret_cast<const f32x4*>(f2 + 128 + 4*k4);
            qq[3] = *reinterpret_cast<const f32x4*>(f3 + 128 + 4*k4);
            LOADW8H(wB, wb, 2*k4+1);
            FMAS8H(acc0, wA, qq, 0);
            LOADW8H(wA, wb, (k4 < 15) ? (2*k4+2) : 0);
            FMAS8H(acc0, wB, qq, 1);
        }
    }

    // ---------------- P2: out1 b-part (K=128 w011), cols 4*cc ----------------
    const int c4 = cc * 4;
    float accB[16];
    #pragma unroll
    for (int i = 0; i < 16; ++i) accB[i] = 0.f;
    {
        const float* wb = w011 + c4;
        float4 wA[2], wB[2];
        LOADW4H(wA, wb, 0);
        #pragma unroll 1
        for (int k4 = 0; k4 < 32; ++k4) {
            f32x4 qq[4];
            qq[0] = *reinterpret_cast<const f32x4*>(f0 + 4*k4);
            qq[1] = *reinterpret_cast<const f32x4*>(f1 + 4*k4);
            qq[2] = *reinterpret_cast<const f32x4*>(f2 + 4*k4);
            qq[3] = *reinterpret_cast<const f32x4*>(f3 + 4*k4);
            LOADW4H(wB, wb, 2*k4+1);
            FMAS4H(accB, wA, qq, 0);
            LOADW4H(wA, wb, (k4 < 31) ? (2*k4+2) : 0);
            FMAS4H(accB, wB, qq, 1);
        }
    }
    __syncthreads();   // featA reads done

    // ---------------- stage out0 -> LDS (already combined), contiguous store ----------------
    #pragma unroll
    for (int r = 0; r < 4; ++r) {
        float* dst = feat + (r0 + r) * FSTR + c8;
        f32x4 v0, v1;
        #pragma unroll
        for (int cj = 0; cj < 4; ++cj) { v0[cj] = acc0[r*8+cj]; v1[cj] = acc0[r*8+4+cj]; }
        *reinterpret_cast<f32x4*>(dst)     = v0;
        *reinterpret_cast<f32x4*>(dst + 4) = v1;
    }
    __syncthreads();
    {   // global store out0: lane=row, 128 B contiguous per thread
        const float* srow = feat + row * FSTR + 32*q;
        float* orow = out + (rbase + row)*OUTD + 32*q;
        #pragma unroll
        for (int i = 0; i < 8; ++i)
            *reinterpret_cast<float4*>(orow + 4*i) =
                *reinterpret_cast<const float4*>(srow + 4*i);
    }
    __syncthreads();   // out0 LDS reads done before featT overwrite

    // ---------------- stage T: featT = [v0 | v1 | v2] ----------------
    {
        float qf[48];
        #pragma unroll
        for (int c = 0; c < 12; ++c) {
            float4 v = ld4(x1r + 128 + 48*q + 4*c);
            qf[4*c+0]=v.x; qf[4*c+1]=v.y; qf[4*c+2]=v.z; qf[4*c+3]=v.w;
        }
        #pragma unroll
        for (int i = 0; i < 16; ++i) {
            const int u = 16*q + i;
            frS[u]       = qf[3*i+0];
            frS[64 + u]  = qf[3*i+1];
            frS[128 + u] = qf[3*i+2];
        }
    }
    __syncthreads();

    // ---------------- P4 first (lane=row): out2 G-part, then epilogue store (frees accG) ----------------
    {
        float accG0[8], accG1[8], accG2[8];
        #pragma unroll
        for (int i = 0; i < 8; ++i) { accG0[i]=0.f; accG1[i]=0.f; accG2[i]=0.f; }
        const float* frC = feat + row * FSTR;
        const int wb = wvu * 8;
        #pragma unroll 1
        for (int ut = 0; ut < 16; ++ut) {
            f32x4 g0 = *reinterpret_cast<const f32x4*>(frC + 4*ut);
            f32x4 g1 = *reinterpret_cast<const f32x4*>(frC + 64 + 4*ut);
            f32x4 g2 = *reinterpret_cast<const f32x4*>(frC + 128 + 4*ut);
            #pragma unroll
            for (int du = 0; du < 4; ++du) {
                const float* wp = w112 + (4*ut+du)*32 + wb;
                float4 wa = ld4(wp);
                float4 wb4 = ld4(wp + 4);
                const float wvals[8] = {wa.x, wa.y, wa.z, wa.w, wb4.x, wb4.y, wb4.z, wb4.w};
                #pragma unroll
                for (int wl = 0; wl < 8; ++wl) {
                    accG0[wl] += g0[du] * wvals[wl];
                    accG1[wl] += g1[du] * wvals[wl];
                    accG2[wl] += g2[du] * wvals[wl];
                }
            }
        }
        // out2 epilogue: cross(G, v)*INV6, direct store
        const float v6x = scal[row*SCAL_STR+5];
        const float v6y = scal[row*SCAL_STR+6];
        const float v6z = scal[row*SCAL_STR+7];
        float ov[24];
        #pragma unroll
        for (int wl = 0; wl < 8; ++wl) {
            ov[3*wl+0] = accG1[wl]*v6z - accG2[wl]*v6y;
            ov[3*wl+1] = accG2[wl]*v6x - accG0[wl]*v6z;
            ov[3*wl+2] = accG0[wl]*v6y - accG1[wl]*v6x;
        }
        float* orow = out + (rbase + row)*OUTD + 320 + 24*wvu;
        #pragma unroll
        for (int qq = 0; qq < 6; ++qq)
            *reinterpret_cast<float4*>(orow + 4*qq) =
                make_float4(ov[4*qq], ov[4*qq+1], ov[4*qq+2], ov[4*qq+3]);
    }

    // ---------------- P3: out1 e-part (K=64 w101, 3 comps), weights hoisted across comps ----------------
    float accE0[16], accE1[16], accE2[16];
    #pragma unroll
    for (int i = 0; i < 16; ++i) { accE0[i]=0.f; accE1[i]=0.f; accE2[i]=0.f; }
    {
        const float* wb = w101 + c4;
        #pragma unroll 1
        for (int u4 = 0; u4 < 16; ++u4) {
            float4 w[4];
            const float* wp = wb + (size_t)(4*u4)*64;
            w[0] = ld4(wp);       w[1] = ld4(wp + 64);
            w[2] = ld4(wp + 128); w[3] = ld4(wp + 192);
            FMAS4(accE0, w, 4*u4);
            FMAS4(accE1, w, 64 + 4*u4);
            FMAS4(accE2, w, 128 + 4*u4);
        }
    }
    __syncthreads();   // featT reads done

    // ---------------- stage out1 -> LDS (combine), contiguous store ----------------
    #pragma unroll
    for (int r = 0; r < 4; ++r) {
        const int rw = r0 + r;
        const float s2I = scal[rw*SCAL_STR+1];
        const float vxI = scal[rw*SCAL_STR+2];
        const float vyI = scal[rw*SCAL_STR+3];
        const float vzI = scal[rw*SCAL_STR+4];
        float vals[12];
        #pragma unroll
        for (int cj = 0; cj < 4; ++cj) {
            const float b = accB[r*4+cj];
            vals[3*cj+0] = vxI*b + s2I*accE0[r*4+cj];
            vals[3*cj+1] = vyI*b + s2I*accE1[r*4+cj];
            vals[3*cj+2] = vzI*b + s2I*accE2[r*4+cj];
        }
        float* dst = feat + rw * FSTR + 12*cc;
        *reinterpret_cast<f32x4*>(dst)     = *reinterpret_cast<const f32x4*>(vals);
        *reinterpret_cast<f32x4*>(dst + 4) = *reinterpret_cast<const f32x4*>(vals + 4);
        *reinterpret_cast<f32x4*>(dst + 8) = *reinterpret_cast<const f32x4*>(vals + 8);
    }
    __syncthreads();
    {   // global store out1: lane=row, 192 B contiguous per thread
        const float* srow = feat + row * FSTR + 48*q;
        float* orow = out + (rbase + row)*OUTD + 128 + 48*q;
        #pragma unroll
        for (int i = 0; i < 12; ++i)
            *reinterpret_cast<float4*>(orow + 4*i) =
                *reinterpret_cast<const float4*>(srow + 4*i);
    }

    #undef LOADW8H
    #undef FMAS8H
    #undef LOADW4H
    #undef FMAS4H
    #undef FMAS4
}

extern "C" void kernel_launch(void* const* d_in, const int* in_sizes, int n_in,
                              void* d_out, int out_size, void* d_ws, size_t ws_size,
                              hipStream_t stream) {
    const float* x1   = (const float*)d_in[0];
    const float* x2   = (const float*)d_in[1];
    const float* w000 = (const float*)d_in[2];
    const float* w011 = (const float*)d_in[3];
    const float* w101 = (const float*)d_in[4];
    const float* w110 = (const float*)d_in[5];
    const float* w112 = (const float*)d_in[6];
    // d_in[7] = w3j111 — folded analytically (cross with v2, scaled 1/sqrt6).
    float* out = (float*)d_out;

    tp_valu_v10<<<dim3(NBLK), dim3(256), 0, stream>>>(
        x1, x2, w000, w011, w101, w110, w112, out);
}

// Round 11
// 412.463 us; speedup vs baseline: 3.2458x; 1.0446x over previous
//
#include <hip/hip_runtime.h>

#define M_ROWS 200000
#define NROWS  64            // rows per block
#define NBLK   3125          // 200000 / 64, exact
#define DIM1   320
#define OUTD   416
#define FSTR   196           // feat row stride (floats)

#define SCAL_STR 9
#define SCAL_OFF (NROWS * FSTR)
#define LDS_FLOATS (SCAL_OFF + NROWS * SCAL_STR)   // 13120 floats = 52480 B

typedef __attribute__((ext_vector_type(4))) float f32x4;

static __device__ __forceinline__ float4 ld4(const float* p) {
    return *reinterpret_cast<const float4*>(p);
}

// (256,2): (256,3) drove the allocator to 84 VGPR and spilled everything (R8).
// Live-set kept < ~115: merged out0 acc (s2*A then +=D), P2 fused into P1-A,
// 2-k transient weight chunks. Plain loads + unroll 2 (R6-style): compiler
// schedules better than manual dbuf + unroll 1 (R10: 430us vs R6: 363us).
__global__ __launch_bounds__(256, 2)
void tp_valu_v11(const float* __restrict__ x1,
                 const float* __restrict__ x2,
                 const float* __restrict__ w000,
                 const float* __restrict__ w011,
                 const float* __restrict__ w101,
                 const float* __restrict__ w110,
                 const float* __restrict__ w112,
                 float* __restrict__ out) {
    __shared__ __align__(16) float lds[LDS_FLOATS];
    float* feat = lds;
    float* scal = lds + SCAL_OFF;

    constexpr float INV3 = 0.57735026918962576f;   // 1/sqrt(3)
    constexpr float INV6 = 0.40824829046386302f;   // 1/sqrt(6)

    const int t   = threadIdx.x;
    const int row = t & 63;                        // staging / store row
    const int q   = t >> 6;                        // wave id
    const int wvu = __builtin_amdgcn_readfirstlane(q);
    const long rbase = (long)blockIdx.x * NROWS;

    const float* x1r = x1 + (rbase + row) * DIM1;
    float* frS = feat + row * FSTR;

    const float4 xr2 = ld4(x2 + (rbase + row) * 4);
    const float s2 = xr2.x, vx = xr2.y, vy = xr2.z, vz = xr2.w;
    if (q == 0) {
        scal[row*SCAL_STR+0] = s2;
        scal[row*SCAL_STR+1] = s2 * INV3;
        scal[row*SCAL_STR+2] = vx * INV3;
        scal[row*SCAL_STR+3] = vy * INV3;
        scal[row*SCAL_STR+4] = vz * INV3;
        scal[row*SCAL_STR+5] = vx * INV6;
        scal[row*SCAL_STR+6] = vy * INV6;
        scal[row*SCAL_STR+7] = vz * INV6;
    }

    // ---------------- stage S: featA = [x1s raw (0..127) | d*INV3 (128..191)] ----------------
    {
        #pragma unroll
        for (int i = 0; i < 8; ++i) {
            float4 v = ld4(x1r + q*32 + 4*i);
            *reinterpret_cast<float4*>(frS + q*32 + 4*i) = v;
        }
        float qf[48];
        #pragma unroll
        for (int c = 0; c < 12; ++c) {
            float4 v = ld4(x1r + 128 + 48*q + 4*c);
            qf[4*c+0]=v.x; qf[4*c+1]=v.y; qf[4*c+2]=v.z; qf[4*c+3]=v.w;
        }
        #pragma unroll
        for (int i = 0; i < 16; ++i) {
            const int u = 16*q + i;
            frS[128 + u] = (qf[3*i]*vx + qf[3*i+1]*vy + qf[3*i+2]*vz) * INV3;
        }
    }
    __syncthreads();

    // compute-phase thread map: 4 rows per thread (quad), col chunk cc
    const int quad = t >> 4;                       // 0..15 -> rows 4*quad..4*quad+3
    const int cc   = t & 15;
    const int r0   = 4 * quad;
    const float* f0 = feat + (r0 + 0) * FSTR;
    const float* f1 = feat + (r0 + 1) * FSTR;
    const float* f2 = feat + (r0 + 2) * FSTR;
    const float* f3 = feat + (r0 + 3) * FSTR;

    const int c8 = cc * 8;
    const int c4 = cc * 4;

    // ---------------- P1-A + P2 fused: featA k=0..127 -> acc0 (w000) and accB (w011) ----------------
    float acc0[32];
    float accB[16];
    #pragma unroll
    for (int i = 0; i < 32; ++i) acc0[i] = 0.f;
    #pragma unroll
    for (int i = 0; i < 16; ++i) accB[i] = 0.f;
    {
        const float* wa = w000 + c8;
        const float* wb = w011 + c4;
        #pragma unroll 2
        for (int kt = 0; kt < 32; ++kt) {          // 4 k per iter
            f32x4 qq[4];
            qq[0] = *reinterpret_cast<const f32x4*>(f0 + 4*kt);
            qq[1] = *reinterpret_cast<const f32x4*>(f1 + 4*kt);
            qq[2] = *reinterpret_cast<const f32x4*>(f2 + 4*kt);
            qq[3] = *reinterpret_cast<const f32x4*>(f3 + 4*kt);
            #pragma unroll
            for (int h = 0; h < 2; ++h) {          // 2-k halves to cap live regs
                float4 w8a = ld4(wa + (size_t)(4*kt + 2*h)*128);
                float4 w8b = ld4(wa + (size_t)(4*kt + 2*h)*128 + 4);
                float4 w8c = ld4(wa + (size_t)(4*kt + 2*h + 1)*128);
                float4 w8d = ld4(wa + (size_t)(4*kt + 2*h + 1)*128 + 4);
                float4 w4a = ld4(wb + (size_t)(4*kt + 2*h)*64);
                float4 w4b = ld4(wb + (size_t)(4*kt + 2*h + 1)*64);
                #pragma unroll
                for (int r = 0; r < 4; ++r) {
                    const float a = qq[r][2*h], b = qq[r][2*h+1];
                    acc0[r*8+0] += a*w8a.x; acc0[r*8+1] += a*w8a.y;
                    acc0[r*8+2] += a*w8a.z; acc0[r*8+3] += a*w8a.w;
                    acc0[r*8+4] += a*w8b.x; acc0[r*8+5] += a*w8b.y;
                    acc0[r*8+6] += a*w8b.z; acc0[r*8+7] += a*w8b.w;
                    acc0[r*8+0] += b*w8c.x; acc0[r*8+1] += b*w8c.y;
                    acc0[r*8+2] += b*w8c.z; acc0[r*8+3] += b*w8c.w;
                    acc0[r*8+4] += b*w8d.x; acc0[r*8+5] += b*w8d.y;
                    acc0[r*8+6] += b*w8d.z; acc0[r*8+7] += b*w8d.w;
                    accB[r*4+0] += a*w4a.x; accB[r*4+1] += a*w4a.y;
                    accB[r*4+2] += a*w4a.z; accB[r*4+3] += a*w4a.w;
                    accB[r*4+0] += b*w4b.x; accB[r*4+1] += b*w4b.y;
                    accB[r*4+2] += b*w4b.z; accB[r*4+3] += b*w4b.w;
                }
            }
        }
    }

    // scale by per-row s2, then accumulate the D-part into the SAME registers
    #pragma unroll
    for (int r = 0; r < 4; ++r) {
        const float s2r = scal[(r0 + r)*SCAL_STR + 0];
        #pragma unroll
        for (int c = 0; c < 8; ++c) acc0[r*8+c] *= s2r;
    }

    // ---------------- P1-D: featA k=128..191 (d*INV3) -> acc0 (w110) ----------------
    {
        const float* wa = w110 + c8;
        #pragma unroll 2
        for (int kt = 0; kt < 16; ++kt) {          // 4 k per iter
            f32x4 qq[4];
            qq[0] = *reinterpret_cast<const f32x4*>(f0 + 128 + 4*kt);
            qq[1] = *reinterpret_cast<const f32x4*>(f1 + 128 + 4*kt);
            qq[2] = *reinterpret_cast<const f32x4*>(f2 + 128 + 4*kt);
            qq[3] = *reinterpret_cast<const f32x4*>(f3 + 128 + 4*kt);
            #pragma unroll
            for (int h = 0; h < 2; ++h) {
                float4 w8a = ld4(wa + (size_t)(4*kt + 2*h)*128);
                float4 w8b = ld4(wa + (size_t)(4*kt + 2*h)*128 + 4);
                float4 w8c = ld4(wa + (size_t)(4*kt + 2*h + 1)*128);
                float4 w8d = ld4(wa + (size_t)(4*kt + 2*h + 1)*128 + 4);
                #pragma unroll
                for (int r = 0; r < 4; ++r) {
                    const float a = qq[r][2*h], b = qq[r][2*h+1];
                    acc0[r*8+0] += a*w8a.x; acc0[r*8+1] += a*w8a.y;
                    acc0[r*8+2] += a*w8a.z; acc0[r*8+3] += a*w8a.w;
                    acc0[r*8+4] += a*w8b.x; acc0[r*8+5] += a*w8b.y;
                    acc0[r*8+6] += a*w8b.z; acc0[r*8+7] += a*w8b.w;
                    acc0[r*8+0] += b*w8c.x; acc0[r*8+1] += b*w8c.y;
                    acc0[r*8+2] += b*w8c.z; acc0[r*8+3] += b*w8c.w;
                    acc0[r*8+4] += b*w8d.x; acc0[r*8+5] += b*w8d.y;
                    acc0[r*8+6] += b*w8d.z; acc0[r*8+7] += b*w8d.w;
                }
            }
        }
    }
    __syncthreads();   // featA reads done

    // ---------------- stage out0 -> LDS (already combined), contiguous store ----------------
    #pragma unroll
    for (int r = 0; r < 4; ++r) {
        float* dst = feat + (r0 + r) * FSTR + c8;
        f32x4 v0, v1;
        #pragma unroll
        for (int cj = 0; cj < 4; ++cj) { v0[cj] = acc0[r*8+cj]; v1[cj] = acc0[r*8+4+cj]; }
        *reinterpret_cast<f32x4*>(dst)     = v0;
        *reinterpret_cast<f32x4*>(dst + 4) = v1;
    }
    __syncthreads();
    {   // global store out0: lane=row, 128 B contiguous per thread
        const float* srow = feat + row * FSTR + 32*q;
        float* orow = out + (rbase + row)*OUTD + 32*q;
        #pragma unroll
        for (int i = 0; i < 8; ++i)
            *reinterpret_cast<float4*>(orow + 4*i) =
                *reinterpret_cast<const float4*>(srow + 4*i);
    }
    __syncthreads();   // out0 LDS reads done before featT overwrite

    // ---------------- stage T: featT = [v0 | v1 | v2] ----------------
    {
        float qf[48];
        #pragma unroll
        for (int c = 0; c < 12; ++c) {
            float4 v = ld4(x1r + 128 + 48*q + 4*c);
            qf[4*c+0]=v.x; qf[4*c+1]=v.y; qf[4*c+2]=v.z; qf[4*c+3]=v.w;
        }
        #pragma unroll
        for (int i = 0; i < 16; ++i) {
            const int u = 16*q + i;
            frS[u]       = qf[3*i+0];
            frS[64 + u]  = qf[3*i+1];
            frS[128 + u] = qf[3*i+2];
        }
    }
    __syncthreads();

    // ---------------- P4 (lane=row): out2 G-part + epilogue store (accG freed before P3) ----------------
    {
        float accG0[8], accG1[8], accG2[8];
        #pragma unroll
        for (int i = 0; i < 8; ++i) { accG0[i]=0.f; accG1[i]=0.f; accG2[i]=0.f; }
        const float* frC = feat + row * FSTR;
        const int wb = wvu * 8;
        #pragma unroll 2
        for (int ut = 0; ut < 16; ++ut) {
            f32x4 g0 = *reinterpret_cast<const f32x4*>(frC + 4*ut);
            f32x4 g1 = *reinterpret_cast<const f32x4*>(frC + 64 + 4*ut);
            f32x4 g2 = *reinterpret_cast<const f32x4*>(frC + 128 + 4*ut);
            #pragma unroll
            for (int du = 0; du < 4; ++du) {
                const float* wp = w112 + (size_t)(4*ut+du)*32 + wb;
                float4 wa = ld4(wp);
                float4 wb4 = ld4(wp + 4);
                const float wvals[8] = {wa.x, wa.y, wa.z, wa.w, wb4.x, wb4.y, wb4.z, wb4.w};
                #pragma unroll
                for (int wl = 0; wl < 8; ++wl) {
                    accG0[wl] += g0[du] * wvals[wl];
                    accG1[wl] += g1[du] * wvals[wl];
                    accG2[wl] += g2[du] * wvals[wl];
                }
            }
        }
        const float v6x = scal[row*SCAL_STR+5];
        const float v6y = scal[row*SCAL_STR+6];
        const float v6z = scal[row*SCAL_STR+7];
        float ov[24];
        #pragma unroll
        for (int wl = 0; wl < 8; ++wl) {
            ov[3*wl+0] = accG1[wl]*v6z - accG2[wl]*v6y;
            ov[3*wl+1] = accG2[wl]*v6x - accG0[wl]*v6z;
            ov[3*wl+2] = accG0[wl]*v6y - accG1[wl]*v6x;
        }
        float* orow = out + (rbase + row)*OUTD + 320 + 24*wvu;
        #pragma unroll
        for (int qq = 0; qq < 6; ++qq)
            *reinterpret_cast<float4*>(orow + 4*qq) =
                make_float4(ov[4*qq], ov[4*qq+1], ov[4*qq+2], ov[4*qq+3]);
    }

    // ---------------- P3: out1 e-part (K=64 w101, 3 comps), weights hoisted across comps ----------------
    float accE0[16], accE1[16], accE2[16];
    #pragma unroll
    for (int i = 0; i < 16; ++i) { accE0[i]=0.f; accE1[i]=0.f; accE2[i]=0.f; }
    {
        const float* wb = w101 + c4;
        #pragma unroll 2
        for (int u4 = 0; u4 < 16; ++u4) {
            float4 w[4];
            const float* wp = wb + (size_t)(4*u4)*64;
            w[0] = ld4(wp);       w[1] = ld4(wp + 64);
            w[2] = ld4(wp + 128); w[3] = ld4(wp + 192);
            #pragma unroll
            for (int comp = 0; comp < 3; ++comp) {
                float* accE = (comp == 0) ? accE0 : (comp == 1) ? accE1 : accE2;
                const int foff = comp * 64 + 4*u4;
                f32x4 qq[4];
                qq[0] = *reinterpret_cast<const f32x4*>(f0 + foff);
                qq[1] = *reinterpret_cast<const f32x4*>(f1 + foff);
                qq[2] = *reinterpret_cast<const f32x4*>(f2 + foff);
                qq[3] = *reinterpret_cast<const f32x4*>(f3 + foff);
                #pragma unroll
                for (int r = 0; r < 4; ++r) {
                    #pragma unroll
                    for (int dk = 0; dk < 4; ++dk) {
                        const float fv = qq[r][dk];
                        accE[r*4+0] += fv*w[dk].x;  accE[r*4+1] += fv*w[dk].y;
                        accE[r*4+2] += fv*w[dk].z;  accE[r*4+3] += fv*w[dk].w;
                    }
                }
            }
        }
    }
    __syncthreads();   // featT reads done

    // ---------------- stage out1 -> LDS (combine), contiguous store ----------------
    #pragma unroll
    for (int r = 0; r < 4; ++r) {
        const int rw = r0 + r;
        const float s2I = scal[rw*SCAL_STR+1];
        const float vxI = scal[rw*SCAL_STR+2];
        const float vyI = scal[rw*SCAL_STR+3];
        const float vzI = scal[rw*SCAL_STR+4];
        float vals[12];
        #pragma unroll
        for (int cj = 0; cj < 4; ++cj) {
            const float b = accB[r*4+cj];
            vals[3*cj+0] = vxI*b + s2I*accE0[r*4+cj];
            vals[3*cj+1] = vyI*b + s2I*accE1[r*4+cj];
            vals[3*cj+2] = vzI*b + s2I*accE2[r*4+cj];
        }
        float* dst = feat + rw * FSTR + 12*cc;
        *reinterpret_cast<f32x4*>(dst)     = *reinterpret_cast<const f32x4*>(vals);
        *reinterpret_cast<f32x4*>(dst + 4) = *reinterpret_cast<const f32x4*>(vals + 4);
        *reinterpret_cast<f32x4*>(dst + 8) = *reinterpret_cast<const f32x4*>(vals + 8);
    }
    __syncthreads();
    {   // global store out1: lane=row, 192 B contiguous per thread
        const float* srow = feat + row * FSTR + 48*q;
        float* orow = out + (rbase + row)*OUTD + 128 + 48*q;
        #pragma unroll
        for (int i = 0; i < 12; ++i)
            *reinterpret_cast<float4*>(orow + 4*i) =
                *reinterpret_cast<const float4*>(srow + 4*i);
    }
}

extern "C" void kernel_launch(void* const* d_in, const int* in_sizes, int n_in,
                              void* d_out, int out_size, void* d_ws, size_t ws_size,
                              hipStream_t stream) {
    const float* x1   = (const float*)d_in[0];
    const float* x2   = (const float*)d_in[1];
    const float* w000 = (const float*)d_in[2];
    const float* w011 = (const float*)d_in[3];
    const float* w101 = (const float*)d_in[4];
    const float* w110 = (const float*)d_in[5];
    const float* w112 = (const float*)d_in[6];
    // d_in[7] = w3j111 — folded analytically (cross with v2, scaled 1/sqrt6).
    float* out = (float*)d_out;

    tp_valu_v11<<<dim3(NBLK), dim3(256), 0, stream>>>(
        x1, x2, w000, w011, w101, w110, w112, out);
}

// Round 12
// 337.193 us; speedup vs baseline: 3.9703x; 1.2232x over previous
//
#include <hip/hip_runtime.h>

#define M_ROWS 200000
#define NROWS  64            // rows per block = lanes per wave
#define NBLK   3125          // 200000 / 64, exact
#define DIM1   320
#define OUTD   416
#define FSTR   196           // featV row stride (floats)
#define LDS_FLOATS (NROWS * FSTR)   // 12544 floats = 50176 B

typedef __attribute__((ext_vector_type(4))) float f32x4;

static __device__ __forceinline__ float4 ld4(const float* p) {
    return *reinterpret_cast<const float4*>(p);
}

// lane=row map: weight addresses are wave-uniform (only loop vars + readfirstlane'd
// wave id) -> compiler emits scalar s_loads; weights stream through the scalar cache
// in SGPRs, off the VALU/VMEM critical path (R6 evidence: VGPR 68, VALU issue ~= FMA-only).
// One LDS staging (raw x1v), ONE barrier. x1 is read exactly once from global.
__global__ __launch_bounds__(256, 2)
void tp_valu_v12(const float* __restrict__ x1,
                 const float* __restrict__ x2,
                 const float* __restrict__ w000,
                 const float* __restrict__ w011,
                 const float* __restrict__ w101,
                 const float* __restrict__ w110,
                 const float* __restrict__ w112,
                 float* __restrict__ out) {
    __shared__ __align__(16) float featV[LDS_FLOATS];

    constexpr float INV3 = 0.57735026918962576f;   // 1/sqrt(3)
    constexpr float INV6 = 0.40824829046386302f;   // 1/sqrt(6)

    const int t   = threadIdx.x;
    const int row = t & 63;
    const int q   = t >> 6;                        // wave id = staging quarter
    const int wv  = __builtin_amdgcn_readfirstlane(q);
    const long rbase = (long)blockIdx.x * NROWS;

    const float* x1r = x1 + (rbase + row) * DIM1;
    float* frS = featV + row * FSTR;

    // per-row x2-derived constants, kept in registers for the whole kernel
    const float4 xr2 = ld4(x2 + (rbase + row) * 4);
    const float s2  = xr2.x;
    const float s2I = s2 * INV3;
    const float vxI = xr2.y * INV3, vyI = xr2.z * INV3, vzI = xr2.w * INV3;
    const float v6x = xr2.y * INV6, v6y = xr2.z * INV6, v6z = xr2.w * INV6;

    // ---- stage featV = [v0 (0:64) | v1 (64:128) | v2 (128:192)]; thread covers u=16q..16q+15 ----
    {
        float qf[48];
        #pragma unroll
        for (int c = 0; c < 12; ++c) {
            float4 v = ld4(x1r + 128 + 48*q + 4*c);
            qf[4*c+0]=v.x; qf[4*c+1]=v.y; qf[4*c+2]=v.z; qf[4*c+3]=v.w;
        }
        #pragma unroll
        for (int i = 0; i < 16; ++i) {
            const int u = 16*q + i;
            frS[u]       = qf[3*i+0];
            frS[64 + u]  = qf[3*i+1];
            frS[128 + u] = qf[3*i+2];
        }
    }
    __syncthreads();                               // the kernel's ONLY barrier

    const int c32 = wv * 32, c16 = wv * 16, c8 = wv * 8;

    // ---- F1: ONE x1s pass (global, per-lane row) -> accA[32] (w000) + accB[16] (w011) ----
    float accA[32], accB[16];
    #pragma unroll
    for (int i = 0; i < 32; ++i) accA[i] = 0.f;
    #pragma unroll
    for (int i = 0; i < 16; ++i) accB[i] = 0.f;
    {
        const float* wa = w000 + c32;
        const float* wb = w011 + c16;
        #pragma unroll 2
        for (int kt = 0; kt < 16; ++kt) {          // 8 k per tile
            f32x4 xs0 = *reinterpret_cast<const f32x4*>(x1r + kt*8);
            f32x4 xs1 = *reinterpret_cast<const f32x4*>(x1r + kt*8 + 4);
            #pragma unroll
            for (int j = 0; j < 8; ++j) {
                const float fv = (j < 4) ? xs0[j] : xs1[j-4];
                const float* wpA = wa + (size_t)(kt*8 + j) * 128;
                const float* wpB = wb + (size_t)(kt*8 + j) * 64;
                #pragma unroll
                for (int c = 0; c < 8; ++c) {
                    float4 w = ld4(wpA + 4*c);
                    accA[4*c+0] += fv*w.x; accA[4*c+1] += fv*w.y;
                    accA[4*c+2] += fv*w.z; accA[4*c+3] += fv*w.w;
                }
                #pragma unroll
                for (int c = 0; c < 4; ++c) {
                    float4 w = ld4(wpB + 4*c);
                    accB[4*c+0] += fv*w.x; accB[4*c+1] += fv*w.y;
                    accB[4*c+2] += fv*w.z; accB[4*c+3] += fv*w.w;
                }
            }
        }
    }
    #pragma unroll
    for (int i = 0; i < 32; ++i) accA[i] *= s2;    // out0 = s2*A ...

    // ---- F2: d pass (LDS v streams) -> accA += (x1v·v2)*INV3 @ w110, same registers ----
    {
        const float* wa = w110 + c32;
        #pragma unroll 2
        for (int ut = 0; ut < 8; ++ut) {           // 8 u per tile
            f32x4 a0 = *reinterpret_cast<const f32x4*>(frS + 8*ut);
            f32x4 a1 = *reinterpret_cast<const f32x4*>(frS + 8*ut + 4);
            f32x4 b0 = *reinterpret_cast<const f32x4*>(frS + 64 + 8*ut);
            f32x4 b1 = *reinterpret_cast<const f32x4*>(frS + 64 + 8*ut + 4);
            f32x4 c0 = *reinterpret_cast<const f32x4*>(frS + 128 + 8*ut);
            f32x4 c1 = *reinterpret_cast<const f32x4*>(frS + 128 + 8*ut + 4);
            float d[8];
            #pragma unroll
            for (int j = 0; j < 4; ++j) {
                d[j]   = a0[j]*vxI + b0[j]*vyI + c0[j]*vzI;
                d[4+j] = a1[j]*vxI + b1[j]*vyI + c1[j]*vzI;
            }
            #pragma unroll
            for (int j = 0; j < 8; ++j) {
                const float fv = d[j];
                const float* wp = wa + (size_t)(8*ut + j) * 128;
                #pragma unroll
                for (int c = 0; c < 8; ++c) {
                    float4 w = ld4(wp + 4*c);
                    accA[4*c+0] += fv*w.x; accA[4*c+1] += fv*w.y;
                    accA[4*c+2] += fv*w.z; accA[4*c+3] += fv*w.w;
                }
            }
        }
    }
    // store out0: 128 B contiguous per lane (4 waves cover cols 0..127)
    {
        float* orow = out + (rbase + row)*OUTD + c32;
        #pragma unroll
        for (int i = 0; i < 8; ++i)
            *reinterpret_cast<float4*>(orow + 4*i) =
                make_float4(accA[4*i], accA[4*i+1], accA[4*i+2], accA[4*i+3]);
    }

    // ---- F3: e pass (LDS v streams) -> e[3][16] (w101); combine with held accB ----
    float e0[16], e1[16], e2[16];
    #pragma unroll
    for (int i = 0; i < 16; ++i) { e0[i]=0.f; e1[i]=0.f; e2[i]=0.f; }
    {
        const float* wb = w101 + c16;
        #pragma unroll 2
        for (int ut = 0; ut < 8; ++ut) {
            f32x4 a0 = *reinterpret_cast<const f32x4*>(frS + 8*ut);
            f32x4 a1 = *reinterpret_cast<const f32x4*>(frS + 8*ut + 4);
            f32x4 b0 = *reinterpret_cast<const f32x4*>(frS + 64 + 8*ut);
            f32x4 b1 = *reinterpret_cast<const f32x4*>(frS + 64 + 8*ut + 4);
            f32x4 c0 = *reinterpret_cast<const f32x4*>(frS + 128 + 8*ut);
            f32x4 c1 = *reinterpret_cast<const f32x4*>(frS + 128 + 8*ut + 4);
            #pragma unroll
            for (int j = 0; j < 8; ++j) {
                const float fa = (j < 4) ? a0[j] : a1[j-4];
                const float fb = (j < 4) ? b0[j] : b1[j-4];
                const float fc = (j < 4) ? c0[j] : c1[j-4];
                const float* wp = wb + (size_t)(8*ut + j) * 64;
                #pragma unroll
                for (int c = 0; c < 4; ++c) {
                    float4 w = ld4(wp + 4*c);
                    e0[4*c+0] += fa*w.x; e0[4*c+1] += fa*w.y;
                    e0[4*c+2] += fa*w.z; e0[4*c+3] += fa*w.w;
                    e1[4*c+0] += fb*w.x; e1[4*c+1] += fb*w.y;
                    e1[4*c+2] += fb*w.z; e1[4*c+3] += fb*w.w;
                    e2[4*c+0] += fc*w.x; e2[4*c+1] += fc*w.y;
                    e2[4*c+2] += fc*w.z; e2[4*c+3] += fc*w.w;
                }
            }
        }
    }
    // out1 epilogue + store: 192 B contiguous per lane at 128 + wv*48
    {
        float vals[48];
        #pragma unroll
        for (int c = 0; c < 16; ++c) {
            const float b = accB[c];
            vals[3*c+0] = vxI*b + s2I*e0[c];
            vals[3*c+1] = vyI*b + s2I*e1[c];
            vals[3*c+2] = vzI*b + s2I*e2[c];
        }
        float* orow = out + (rbase + row)*OUTD + 128 + wv*48;
        #pragma unroll
        for (int i = 0; i < 12; ++i)
            *reinterpret_cast<float4*>(orow + 4*i) =
                make_float4(vals[4*i], vals[4*i+1], vals[4*i+2], vals[4*i+3]);
    }

    // ---- F4: G pass (LDS v streams) -> g[3][8] (w112); cross epilogue ----
    float g0[8], g1[8], g2[8];
    #pragma unroll
    for (int i = 0; i < 8; ++i) { g0[i]=0.f; g1[i]=0.f; g2[i]=0.f; }
    {
        const float* wb = w112 + c8;
        #pragma unroll 2
        for (int ut = 0; ut < 8; ++ut) {
            f32x4 a0 = *reinterpret_cast<const f32x4*>(frS + 8*ut);
            f32x4 a1 = *reinterpret_cast<const f32x4*>(frS + 8*ut + 4);
            f32x4 b0 = *reinterpret_cast<const f32x4*>(frS + 64 + 8*ut);
            f32x4 b1 = *reinterpret_cast<const f32x4*>(frS + 64 + 8*ut + 4);
            f32x4 c0 = *reinterpret_cast<const f32x4*>(frS + 128 + 8*ut);
            f32x4 c1 = *reinterpret_cast<const f32x4*>(frS + 128 + 8*ut + 4);
            #pragma unroll
            for (int j = 0; j < 8; ++j) {
                const float fa = (j < 4) ? a0[j] : a1[j-4];
                const float fb = (j < 4) ? b0[j] : b1[j-4];
                const float fc = (j < 4) ? c0[j] : c1[j-4];
                const float* wp = wb + (size_t)(8*ut + j) * 32;
                float4 wA = ld4(wp);
                float4 wB = ld4(wp + 4);
                const float wvv[8] = {wA.x, wA.y, wA.z, wA.w, wB.x, wB.y, wB.z, wB.w};
                #pragma unroll
                for (int wl = 0; wl < 8; ++wl) {
                    g0[wl] += fa * wvv[wl];
                    g1[wl] += fb * wvv[wl];
                    g2[wl] += fc * wvv[wl];
                }
            }
        }
    }
    // out2 epilogue: cross(G, v)*INV6, 96 B contiguous per lane at 320 + wv*24
    {
        float ov[24];
        #pragma unroll
        for (int wl = 0; wl < 8; ++wl) {
            ov[3*wl+0] = g1[wl]*v6z - g2[wl]*v6y;
            ov[3*wl+1] = g2[wl]*v6x - g0[wl]*v6z;
            ov[3*wl+2] = g0[wl]*v6y - g1[wl]*v6x;
        }
        float* orow = out + (rbase + row)*OUTD + 320 + wv*24;
        #pragma unroll
        for (int i = 0; i < 6; ++i)
            *reinterpret_cast<float4*>(orow + 4*i) =
                make_float4(ov[4*i], ov[4*i+1], ov[4*i+2], ov[4*i+3]);
    }
}

extern "C" void kernel_launch(void* const* d_in, const int* in_sizes, int n_in,
                              void* d_out, int out_size, void* d_ws, size_t ws_size,
                              hipStream_t stream) {
    const float* x1   = (const float*)d_in[0];
    const float* x2   = (const float*)d_in[1];
    const float* w000 = (const float*)d_in[2];
    const float* w011 = (const float*)d_in[3];
    const float* w101 = (const float*)d_in[4];
    const float* w110 = (const float*)d_in[5];
    const float* w112 = (const float*)d_in[6];
    // d_in[7] = w3j111 — folded analytically (cross with v2, scaled 1/sqrt6).
    float* out = (float*)d_out;

    tp_valu_v12<<<dim3(NBLK), dim3(256), 0, stream>>>(
        x1, x2, w000, w011, w101, w110, w112, out);
}

// Round 13
// 326.157 us; speedup vs baseline: 4.1046x; 1.0338x over previous
//
#include <hip/hip_runtime.h>

#define M_ROWS 200000
#define NROWS  64            // rows per block = lanes per wave
#define NBLK   3125          // 200000 / 64, exact
#define DIM1   320
#define OUTD   416
#define FSTR   196           // featV row stride (floats); 196 mod 32 = 4 -> conflict-free (R12: 0)
#define LDS_FLOATS (NROWS * FSTR)   // 12544 floats = 50176 B

typedef __attribute__((ext_vector_type(4))) float f32x4;

static __device__ __forceinline__ float4 ld4(const float* p) {
    return *reinterpret_cast<const float4*>(p);
}

// R12 structure (lane=row, SGPR-scalarized weights, one staging + one barrier,
// x1 read once) widened to 8 waves per 64-row block: LDS/block unchanged ->
// ~2x resident waves per CU (latency hiding was the R12 limiter: VALUBusy 44%,
// occ 30%). Each wave takes half the R12 column chunk; accumulator live-set ~50
// -> target VGPR <= 64 (8 waves/SIMD band per m69 occupancy steps).
__global__ __launch_bounds__(512, 4)
void tp_valu_v13(const float* __restrict__ x1,
                 const float* __restrict__ x2,
                 const float* __restrict__ w000,
                 const float* __restrict__ w011,
                 const float* __restrict__ w101,
                 const float* __restrict__ w110,
                 const float* __restrict__ w112,
                 float* __restrict__ out) {
    __shared__ __align__(16) float featV[LDS_FLOATS];

    constexpr float INV3 = 0.57735026918962576f;   // 1/sqrt(3)
    constexpr float INV6 = 0.40824829046386302f;   // 1/sqrt(6)

    const int t   = threadIdx.x;
    const int row = t & 63;
    const int q   = t >> 6;                        // wave id 0..7
    const int wv  = __builtin_amdgcn_readfirstlane(q);
    const long rbase = (long)blockIdx.x * NROWS;

    const float* x1r = x1 + (rbase + row) * DIM1;
    float* frS = featV + row * FSTR;

    // per-row x2-derived constants, kept in registers for the whole kernel
    const float4 xr2 = ld4(x2 + (rbase + row) * 4);
    const float s2  = xr2.x;
    const float s2I = s2 * INV3;
    const float vxI = xr2.y * INV3, vyI = xr2.z * INV3, vzI = xr2.w * INV3;
    const float v6x = xr2.y * INV6, v6y = xr2.z * INV6, v6z = xr2.w * INV6;

    // ---- stage featV = [v0 (0:64) | v1 (64:128) | v2 (128:192)]; wave q covers u=8q..8q+7 ----
    {
        float qf[24];
        #pragma unroll
        for (int c = 0; c < 6; ++c) {
            float4 v = ld4(x1r + 128 + 24*q + 4*c);
            qf[4*c+0]=v.x; qf[4*c+1]=v.y; qf[4*c+2]=v.z; qf[4*c+3]=v.w;
        }
        #pragma unroll
        for (int i = 0; i < 8; ++i) {
            const int u = 8*q + i;
            frS[u]       = qf[3*i+0];
            frS[64 + u]  = qf[3*i+1];
            frS[128 + u] = qf[3*i+2];
        }
    }
    __syncthreads();                               // the kernel's ONLY barrier

    const int c16 = wv * 16, c8w = wv * 8, c4w = wv * 4;

    // ---- F1: ONE x1s pass (global, per-lane row) -> accA[16] (w000) + accB[8] (w011) ----
    float accA[16], accB[8];
    #pragma unroll
    for (int i = 0; i < 16; ++i) accA[i] = 0.f;
    #pragma unroll
    for (int i = 0; i < 8; ++i) accB[i] = 0.f;
    {
        const float* wa = w000 + c16;
        const float* wb = w011 + c8w;
        #pragma unroll 2
        for (int kt = 0; kt < 16; ++kt) {          // 8 k per tile
            f32x4 xs0 = *reinterpret_cast<const f32x4*>(x1r + kt*8);
            f32x4 xs1 = *reinterpret_cast<const f32x4*>(x1r + kt*8 + 4);
            #pragma unroll
            for (int j = 0; j < 8; ++j) {
                const float fv = (j < 4) ? xs0[j] : xs1[j-4];
                const float* wpA = wa + (size_t)(kt*8 + j) * 128;
                const float* wpB = wb + (size_t)(kt*8 + j) * 64;
                #pragma unroll
                for (int c = 0; c < 4; ++c) {
                    float4 w = ld4(wpA + 4*c);
                    accA[4*c+0] += fv*w.x; accA[4*c+1] += fv*w.y;
                    accA[4*c+2] += fv*w.z; accA[4*c+3] += fv*w.w;
                }
                #pragma unroll
                for (int c = 0; c < 2; ++c) {
                    float4 w = ld4(wpB + 4*c);
                    accB[4*c+0] += fv*w.x; accB[4*c+1] += fv*w.y;
                    accB[4*c+2] += fv*w.z; accB[4*c+3] += fv*w.w;
                }
            }
        }
    }
    #pragma unroll
    for (int i = 0; i < 16; ++i) accA[i] *= s2;    // out0 = s2*A ...

    // ---- F2: d pass (LDS v streams) -> accA += (x1v.v2)*INV3 @ w110, same registers ----
    {
        const float* wa = w110 + c16;
        #pragma unroll 2
        for (int ut = 0; ut < 8; ++ut) {           // 8 u per tile
            f32x4 a0 = *reinterpret_cast<const f32x4*>(frS + 8*ut);
            f32x4 a1 = *reinterpret_cast<const f32x4*>(frS + 8*ut + 4);
            f32x4 b0 = *reinterpret_cast<const f32x4*>(frS + 64 + 8*ut);
            f32x4 b1 = *reinterpret_cast<const f32x4*>(frS + 64 + 8*ut + 4);
            f32x4 c0 = *reinterpret_cast<const f32x4*>(frS + 128 + 8*ut);
            f32x4 c1 = *reinterpret_cast<const f32x4*>(frS + 128 + 8*ut + 4);
            float d[8];
            #pragma unroll
            for (int j = 0; j < 4; ++j) {
                d[j]   = a0[j]*vxI + b0[j]*vyI + c0[j]*vzI;
                d[4+j] = a1[j]*vxI + b1[j]*vyI + c1[j]*vzI;
            }
            #pragma unroll
            for (int j = 0; j < 8; ++j) {
                const float fv = d[j];
                const float* wp = wa + (size_t)(8*ut + j) * 128;
                #pragma unroll
                for (int c = 0; c < 4; ++c) {
                    float4 w = ld4(wp + 4*c);
                    accA[4*c+0] += fv*w.x; accA[4*c+1] += fv*w.y;
                    accA[4*c+2] += fv*w.z; accA[4*c+3] += fv*w.w;
                }
            }
        }
    }
    // store out0: 64 B contiguous per lane (8 waves cover cols 0..127)
    {
        float* orow = out + (rbase + row)*OUTD + c16;
        #pragma unroll
        for (int i = 0; i < 4; ++i)
            *reinterpret_cast<float4*>(orow + 4*i) =
                make_float4(accA[4*i], accA[4*i+1], accA[4*i+2], accA[4*i+3]);
    }

    // ---- F3: e pass (LDS v streams) -> e[3][8] (w101); combine with held accB ----
    float e0[8], e1[8], e2[8];
    #pragma unroll
    for (int i = 0; i < 8; ++i) { e0[i]=0.f; e1[i]=0.f; e2[i]=0.f; }
    {
        const float* wb = w101 + c8w;
        #pragma unroll 2
        for (int ut = 0; ut < 8; ++ut) {
            f32x4 a0 = *reinterpret_cast<const f32x4*>(frS + 8*ut);
            f32x4 a1 = *reinterpret_cast<const f32x4*>(frS + 8*ut + 4);
            f32x4 b0 = *reinterpret_cast<const f32x4*>(frS + 64 + 8*ut);
            f32x4 b1 = *reinterpret_cast<const f32x4*>(frS + 64 + 8*ut + 4);
            f32x4 c0 = *reinterpret_cast<const f32x4*>(frS + 128 + 8*ut);
            f32x4 c1 = *reinterpret_cast<const f32x4*>(frS + 128 + 8*ut + 4);
            #pragma unroll
            for (int j = 0; j < 8; ++j) {
                const float fa = (j < 4) ? a0[j] : a1[j-4];
                const float fb = (j < 4) ? b0[j] : b1[j-4];
                const float fc = (j < 4) ? c0[j] : c1[j-4];
                const float* wp = wb + (size_t)(8*ut + j) * 64;
                #pragma unroll
                for (int c = 0; c < 2; ++c) {
                    float4 w = ld4(wp + 4*c);
                    e0[4*c+0] += fa*w.x; e0[4*c+1] += fa*w.y;
                    e0[4*c+2] += fa*w.z; e0[4*c+3] += fa*w.w;
                    e1[4*c+0] += fb*w.x; e1[4*c+1] += fb*w.y;
                    e1[4*c+2] += fb*w.z; e1[4*c+3] += fb*w.w;
                    e2[4*c+0] += fc*w.x; e2[4*c+1] += fc*w.y;
                    e2[4*c+2] += fc*w.z; e2[4*c+3] += fc*w.w;
                }
            }
        }
    }
    // out1 epilogue + store: 96 B contiguous per lane at 128 + wv*24
    {
        float vals[24];
        #pragma unroll
        for (int c = 0; c < 8; ++c) {
            const float b = accB[c];
            vals[3*c+0] = vxI*b + s2I*e0[c];
            vals[3*c+1] = vyI*b + s2I*e1[c];
            vals[3*c+2] = vzI*b + s2I*e2[c];
        }
        float* orow = out + (rbase + row)*OUTD + 128 + wv*24;
        #pragma unroll
        for (int i = 0; i < 6; ++i)
            *reinterpret_cast<float4*>(orow + 4*i) =
                make_float4(vals[4*i], vals[4*i+1], vals[4*i+2], vals[4*i+3]);
    }

    // ---- F4: G pass (LDS v streams) -> g[3][4] (w112); cross epilogue ----
    float g0[4], g1[4], g2[4];
    #pragma unroll
    for (int i = 0; i < 4; ++i) { g0[i]=0.f; g1[i]=0.f; g2[i]=0.f; }
    {
        const float* wb = w112 + c4w;
        #pragma unroll 2
        for (int ut = 0; ut < 8; ++ut) {
            f32x4 a0 = *reinterpret_cast<const f32x4*>(frS + 8*ut);
            f32x4 a1 = *reinterpret_cast<const f32x4*>(frS + 8*ut + 4);
            f32x4 b0 = *reinterpret_cast<const f32x4*>(frS + 64 + 8*ut);
            f32x4 b1 = *reinterpret_cast<const f32x4*>(frS + 64 + 8*ut + 4);
            f32x4 c0 = *reinterpret_cast<const f32x4*>(frS + 128 + 8*ut);
            f32x4 c1 = *reinterpret_cast<const f32x4*>(frS + 128 + 8*ut + 4);
            #pragma unroll
            for (int j = 0; j < 8; ++j) {
                const float fa = (j < 4) ? a0[j] : a1[j-4];
                const float fb = (j < 4) ? b0[j] : b1[j-4];
                const float fc = (j < 4) ? c0[j] : c1[j-4];
                float4 w = ld4(wb + (size_t)(8*ut + j) * 32);
                const float wvv[4] = {w.x, w.y, w.z, w.w};
                #pragma unroll
                for (int wl = 0; wl < 4; ++wl) {
                    g0[wl] += fa * wvv[wl];
                    g1[wl] += fb * wvv[wl];
                    g2[wl] += fc * wvv[wl];
                }
            }
        }
    }
    // out2 epilogue: cross(G, v)*INV6, 48 B contiguous per lane at 320 + wv*12
    {
        float ov[12];
        #pragma unroll
        for (int wl = 0; wl < 4; ++wl) {
            ov[3*wl+0] = g1[wl]*v6z - g2[wl]*v6y;
            ov[3*wl+1] = g2[wl]*v6x - g0[wl]*v6z;
            ov[3*wl+2] = g0[wl]*v6y - g1[wl]*v6x;
        }
        float* orow = out + (rbase + row)*OUTD + 320 + wv*12;
        #pragma unroll
        for (int i = 0; i < 3; ++i)
            *reinterpret_cast<float4*>(orow + 4*i) =
                make_float4(ov[4*i], ov[4*i+1], ov[4*i+2], ov[4*i+3]);
    }
}

extern "C" void kernel_launch(void* const* d_in, const int* in_sizes, int n_in,
                              void* d_out, int out_size, void* d_ws, size_t ws_size,
                              hipStream_t stream) {
    const float* x1   = (const float*)d_in[0];
    const float* x2   = (const float*)d_in[1];
    const float* w000 = (const float*)d_in[2];
    const float* w011 = (const float*)d_in[3];
    const float* w101 = (const float*)d_in[4];
    const float* w110 = (const float*)d_in[5];
    const float* w112 = (const float*)d_in[6];
    // d_in[7] = w3j111 — folded analytically (cross with v2, scaled 1/sqrt6).
    float* out = (float*)d_out;

    tp_valu_v13<<<dim3(NBLK), dim3(512), 0, stream>>>(
        x1, x2, w000, w011, w101, w110, w112, out);
}